// Round 8
// baseline (218.717 us; speedup 1.0000x reference)
//
#include <hip/hip_runtime.h>
#include <stdint.h>

typedef unsigned int u32;
typedef unsigned short u16;

#define N_  1024
#define F_  512
#define ALPHA 0.2f
#define TSTR 68   // k_prep LDS tile stride (u16): 136 B rows -> uint2-aligned reads, ~4-way write conflicts

typedef __attribute__((ext_vector_type(8))) short short8;
typedef __attribute__((ext_vector_type(4))) float float4v;

union Frag { short8 s; u32 u[4]; };

static __device__ __forceinline__ float bits2f(u32 b){ union{u32 u; float f;} c; c.u=b; return c.f; }
static __device__ __forceinline__ u32   f2bits(float f){ union{float f_; u32 u;} c; c.f_=f; return c.u; }
static __device__ __forceinline__ float bflo(u32 p){ return bits2f(p<<16); }
static __device__ __forceinline__ float bfhi(u32 p){ return bits2f(p & 0xffff0000u); }
static __device__ __forceinline__ u32   f2bf(float f){ u32 u=f2bits(f); return (u + 0x7fffu + ((u>>16)&1u))>>16; }

// async global->LDS, 16 B per lane; LDS dest = wave-uniform base + lane*16
static __device__ __forceinline__ void gload_lds16(const void* g, void* l){
    __builtin_amdgcn_global_load_lds((const __attribute__((address_space(1))) u32*)g,
                                     (__attribute__((address_space(3))) u32*)l, 16, 0, 0);
}

// ---- kernel 1: w1 = W^T a1, w2 = W^T a2 (atomic partial sums into ws[0..1024)) ----
__global__ void k_w12(const float* __restrict__ W, const float* __restrict__ a1,
                      const float* __restrict__ a2, float* __restrict__ ws){
    int t = threadIdx.x;          // 256 threads: f = t and t+256
    int bo = blockIdx.x;          // 64 blocks: o-chunk of 8
    float s1a=0.f,s2a=0.f,s1b=0.f,s2b=0.f;
    #pragma unroll
    for(int i=0;i<8;i++){
        int o = bo*8+i;
        float av1 = a1[o], av2 = a2[o];
        float wa = W[o*F_ + t], wb = W[o*F_ + t + 256];
        s1a += wa*av1; s2a += wa*av2; s1b += wb*av1; s2b += wb*av2;
    }
    atomicAdd(&ws[t],       s1a); atomicAdd(&ws[512+t],     s2a);
    atomicAdd(&ws[t+256],   s1b); atomicAdd(&ws[512+t+256], s2b);
}

// ---- kernel 2: fused transpose + dot accumulation (R5 known-good) ----
// X fp32 [b][m][f] -> XT bf16 [b][f][m]; also d1acc[r] += X[r,:].w1, d2acc += X[r,:].w2 (fp32 atomics)
__global__ __launch_bounds__(256)
void k_prep(const float* __restrict__ X, const float* __restrict__ ws,
            u16* __restrict__ XT, float* __restrict__ d1acc, float* __restrict__ d2acc){
    __shared__ u16 tile[64*TSTR];
    const int t  = threadIdx.x;
    const int m0 = blockIdx.x*64, f0 = blockIdx.y*64, b = blockIdx.z;
    const int ml = t>>4, fl4 = (t&15)*4;
    float4 w1q = *(const float4*)(ws + f0 + fl4);
    float4 w2q = *(const float4*)(ws + 512 + f0 + fl4);
    float d1p[4], d2p[4];
    #pragma unroll
    for(int rr=0;rr<4;rr++){
        int m = ml + rr*16;
        float4 v = *(const float4*)(X + ((size_t)(b*N_ + m0 + m))*F_ + f0 + fl4);
        tile[(fl4+0)*TSTR + m] = (u16)f2bf(v.x);
        tile[(fl4+1)*TSTR + m] = (u16)f2bf(v.y);
        tile[(fl4+2)*TSTR + m] = (u16)f2bf(v.z);
        tile[(fl4+3)*TSTR + m] = (u16)f2bf(v.w);
        d1p[rr] = v.x*w1q.x + v.y*w1q.y + v.z*w1q.z + v.w*w1q.w;
        d2p[rr] = v.x*w2q.x + v.y*w2q.y + v.z*w2q.z + v.w*w2q.w;
    }
    #pragma unroll
    for(int s=1;s<16;s<<=1){
        #pragma unroll
        for(int rr=0;rr<4;rr++){ d1p[rr] += __shfl_xor(d1p[rr],s,64); d2p[rr] += __shfl_xor(d2p[rr],s,64); }
    }
    if((t&15)==0){
        #pragma unroll
        for(int rr=0;rr<4;rr++){
            atomicAdd(&d1acc[b*N_ + m0 + ml + rr*16], d1p[rr]);
            atomicAdd(&d2acc[b*N_ + m0 + ml + rr*16], d2p[rr]);
        }
    }
    __syncthreads();
    const int fl = t>>4, ml4 = (t&15)*4;
    #pragma unroll
    for(int rr=0;rr<4;rr++){
        int f = fl + rr*16;
        uint2 val = *(const uint2*)(&tile[f*TSTR + ml4]);
        *(uint2*)(XT + ((size_t)(b*F_ + f0 + f))*N_ + m0 + ml4) = val;
    }
}

// ---- kernel 3: fused scores+softmax+PV+ELU, producer/consumer, 2 blocks/CU ----
// grid (32,16) = 512 blocks = 2 blocks/CU (LDS ~72 KB), 1024 threads = 16 waves.
// 32-row blocks: total score work invariant (P computed once per (row,m) globally);
// extra XT re-reads land in L2 via XCD affinity (32 blocks of batch b on XCD b>>1).
//   PRODUCER: wave w -> rows {w*2, w*2+1} x 32 m, 1 P-value/lane (1 adj int/lane).
//   CONSUMER: wave (nsub=w&1, fq=w>>1) -> 16 rows x 64 f: acc[4], 4 MFMA/iter.
// Double-buffered xbuf, distance-1 staging, distance-2 adj prefetch; plain
// __syncthreads() (vmcnt(0)+lgkmcnt(0) drain) per iter -- drain stall is covered by
// the co-resident second block (32 waves/CU TLP), which 1-block/CU rounds lacked.
__global__ __launch_bounds__(1024, 8)
void k_main(const u16* __restrict__ XT, const int* __restrict__ adj,
            const float* __restrict__ d1acc, const float* __restrict__ d2acc,
            float* __restrict__ out){
    __shared__ u16 xbuf[2][2][8192];   // 64 KB double-buffered X tiles (32 m x 512 f each)
    __shared__ u32 lds_e2[N_];         // 4 KB exp(f2)/exp(.2 f2) bf16-pair table
    __shared__ u16 pbuf[2][2][512];    // 4 KB P A-fragments [buf][nsub][lane*8]
    __shared__ float dsums[32];        // row softmax denominators

    const int t    = threadIdx.x;
    const int lane = t & 63;
    const int wv   = t >> 6;           // 0..15
    const int nsub = wv & 1;           // consumer: row-group of 16
    const int fq   = wv >> 1;          // consumer: f-slice of 64 (0..7)
    const int id   = blockIdx.x + (blockIdx.y << 5);   // 0..511
    const int xcd  = id & 7, slot = id >> 3;           // 64 slots per XCD
    const int b    = (xcd << 1) | (slot >> 5);         // 2 batches per XCD
    const int n0   = (slot & 31) << 5;                 // 32 n-blocks of b per batch
    const int r16  = lane & 15;
    const int quad = lane >> 4;
    // producer mapping: 2 rows/wave, 32 cols/lane-half
    const int rowP  = wv*2 + (lane >> 5);  // 0..31
    const int colP  = lane & 31;
    const int nsubP = rowP >> 4;
    const int pOff  = ((rowP & 15) + ((colP >> 3) << 4))*8 + (colP & 7);

    // exp(f2)/exp(.2*f2) bf16-pair table: 1 entry/thread
    {
        float dv = d2acc[(size_t)b*N_ + t];
        lds_e2[t] = f2bf(__expf(dv)) | (f2bf(__expf(ALPHA*dv))<<16);
    }
    const float d1v  = d1acc[b*N_ + n0 + rowP];
    const float e1pL = __expf(d1v);
    const float e1nL = __expf(ALPHA*d1v);
    const int* adjLane = adj + ((size_t)(b*N_ + n0 + rowP))*N_ + colP;
    const u16* XTb = XT + (size_t)b*F_*N_;

    float dsum = 0.f;

    auto produce = [&](int c, int pb, int ad){
        u32 ev = lds_e2[c*32 + colP];
        float p = fmaxf(e1pL*bflo(ev), e1nL*bfhi(ev));   // lrelu via exp-monotonicity
        p = ad ? p : 0.f;
        dsum += p;
        pbuf[pb][nsubP][pOff] = (u16)f2bf(p);
    };
    auto stage = [&](int mcol, u16 (*buf)[8192]){
        #pragma unroll
        for(int k=0;k<2;k++){
            int idx = wv*2 + k, fhh = idx>>4, c = idx&15;
            const u16* g = XTb + (size_t)(fhh*256 + c*16 + r16)*N_ + mcol + quad*8;
            gload_lds16(g, &buf[fhh][c*512]);
        }
    };

    __syncthreads();                       // lds_e2 ready
    produce(0, 0, adjLane[0]);             // P[0] -> pbuf[0]
    stage(0, xbuf[0]);                     // chunk 0 -> buf 0
    int adU = adjLane[32];                 // adj chunk 1 (for produce(1) in body 0)

    float4v acc[4];
    #pragma unroll
    for(int i=0;i<4;i++) acc[i] = (float4v){0.f,0.f,0.f,0.f};

    int db = 0;
    for(int i=0;i<32;i++){
        __syncthreads();   // drains: stage(i) + adj(i+1) + P[i] LDS writes -> all visible

        if(i < 31) stage((i+1)*32, xbuf[db^1]);          // distance-1 staging
        int adV = (i < 30) ? adjLane[(i+2)*32] : 0;      // distance-2 adj prefetch
        if(i < 31) produce(i+1, (i+1)&1, adU);           // P[i+1] from adj[i+1]

        Frag af;
        { uint4 aw = *(const uint4*)(&pbuf[i&1][nsub][lane*8]);
          af.u[0]=aw.x; af.u[1]=aw.y; af.u[2]=aw.z; af.u[3]=aw.w; }
        // f-slice fq: f = fq*64 + ct*16 + r16 -> fhalf = fq>>2, c = (fq&3)*4 + ct
        const u16* bb = &xbuf[db][fq>>2][((fq&3)*4)*512 + lane*8];  // lane-linear ds_read_b128
        #pragma unroll
        for(int ct=0; ct<4; ct++){
            uint4 bw = *(const uint4*)(bb + ct*512);
            Frag bf_; bf_.u[0]=bw.x; bf_.u[1]=bw.y; bf_.u[2]=bw.z; bf_.u[3]=bw.w;
            acc[ct] = __builtin_amdgcn_mfma_f32_16x16x32_bf16(af.s, bf_.s, acc[ct], 0, 0, 0);
        }
        adU = adV;
        db ^= 1;
    }

    // ---- softmax denominators: reduce over colP (lane bits 0..4) ----
    dsum += __shfl_xor(dsum, 1, 64);
    dsum += __shfl_xor(dsum, 2, 64);
    dsum += __shfl_xor(dsum, 4, 64);
    dsum += __shfl_xor(dsum, 8, 64);
    dsum += __shfl_xor(dsum, 16, 64);
    if(colP == 0) dsums[rowP] = dsum;
    __syncthreads();                       // also drains any tail VMEM before LDS reuse/exit
    float invr[4];
    #pragma unroll
    for(int r=0;r<4;r++) invr[r] = 1.0f / fmaxf(dsums[nsub*16 + quad*4 + r], 1e-30f);

    // ---- epilogue: scale, ELU, fp32 store ----
    #pragma unroll
    for(int ct=0; ct<4; ct++){
        #pragma unroll
        for(int r=0;r<4;r++){
            float v = acc[ct][r] * invr[r];
            v = (v > 0.f) ? v : (__expf(v) - 1.f);
            int n_out = n0 + nsub*16 + quad*4 + r;
            out[((size_t)(b*N_ + n_out))*F_ + fq*64 + ct*16 + r16] = v;
        }
    }
}

extern "C" void kernel_launch(void* const* d_in, const int* in_sizes, int n_in,
                              void* d_out, int out_size, void* d_ws, size_t ws_size,
                              hipStream_t stream) {
    const float* X  = (const float*)d_in[0];   // [16,1024,512] fp32
    const int* adj  = (const int*)d_in[1];     // [16,1024,1024] int32
    const float* W  = (const float*)d_in[2];   // [512,512] fp32
    const float* a1 = (const float*)d_in[3];   // [512]
    const float* a2 = (const float*)d_in[4];   // [512]
    float* out = (float*)d_out;                // [16,1024,512] fp32

    float* ws    = (float*)d_ws;
    float* d1acc = ws + 1024;                  // raw sums; exp'd inside k_main
    float* d2acc = ws + 1024 + 16384;
    u16*  XT     = (u16*)(ws + 50176);         // 16.78 MB bf16 [b][f][m]

    hipMemsetAsync(ws, 0, 33792*sizeof(float), stream);   // zero w1/w2 + d1acc + d2acc
    k_w12<<<64, 256, 0, stream>>>(W, a1, a2, ws);
    k_prep<<<dim3(16, 8, 16), 256, 0, stream>>>(X, ws, XT, d1acc, d2acc);
    k_main<<<dim3(32, 16), 1024, 0, stream>>>(XT, adj, d1acc, d2acc, out);
}

// Round 9
// 185.190 us; speedup vs baseline: 1.1810x; 1.1810x over previous
//
#include <hip/hip_runtime.h>
#include <stdint.h>

typedef unsigned int u32;
typedef unsigned short u16;

#define N_  1024
#define F_  512
#define ALPHA 0.2f
#define TSTR2 72   // k_prep LDS tile stride (u16): 144 B rows -> 16B-aligned b128 reads, 2-way (free)

typedef __attribute__((ext_vector_type(8))) short short8;
typedef __attribute__((ext_vector_type(4))) float float4v;

union Frag { short8 s; u32 u[4]; };

static __device__ __forceinline__ float bits2f(u32 b){ union{u32 u; float f;} c; c.u=b; return c.f; }
static __device__ __forceinline__ u32   f2bits(float f){ union{float f_; u32 u;} c; c.f_=f; return c.u; }
static __device__ __forceinline__ float bflo(u32 p){ return bits2f(p<<16); }
static __device__ __forceinline__ float bfhi(u32 p){ return bits2f(p & 0xffff0000u); }
static __device__ __forceinline__ u32   f2bf(float f){ u32 u=f2bits(f); return (u + 0x7fffu + ((u>>16)&1u))>>16; }
static __device__ __forceinline__ u32   cvt_pk_bf16(float lo, float hi){
    u32 r; asm("v_cvt_pk_bf16_f32 %0, %1, %2" : "=v"(r) : "v"(lo), "v"(hi)); return r;
}

// async global->LDS, 16 B per lane; LDS dest = wave-uniform base + lane*16
static __device__ __forceinline__ void gload_lds16(const void* g, void* l){
    __builtin_amdgcn_global_load_lds((const __attribute__((address_space(1))) u32*)g,
                                     (__attribute__((address_space(3))) u32*)l, 16, 0, 0);
}

// ---- kernel 1: w1 = W^T a1, w2 = W^T a2 (atomic partial sums into ws[0..1024)) ----
__global__ void k_w12(const float* __restrict__ W, const float* __restrict__ a1,
                      const float* __restrict__ a2, float* __restrict__ ws){
    int t = threadIdx.x;          // 256 threads: f = t and t+256
    int bo = blockIdx.x;          // 64 blocks: o-chunk of 8
    float s1a=0.f,s2a=0.f,s1b=0.f,s2b=0.f;
    #pragma unroll
    for(int i=0;i<8;i++){
        int o = bo*8+i;
        float av1 = a1[o], av2 = a2[o];
        float wa = W[o*F_ + t], wb = W[o*F_ + t + 256];
        s1a += wa*av1; s2a += wa*av2; s1b += wb*av1; s2b += wb*av2;
    }
    atomicAdd(&ws[t],       s1a); atomicAdd(&ws[512+t],     s2a);
    atomicAdd(&ws[t+256],   s1b); atomicAdd(&ws[512+t+256], s2b);
}

// ---- kernel 2 (rewritten): transpose X->XT bf16 + d1/d2 dots, one block per (b, 64-row tile) ----
// grid (16,16) = 256 blocks (XCD-affine, matches k_main), 1024 threads = 16 waves.
// Thread (g = t>>8 slice-group 0..3, mg = (t&255)>>4, fq = (t&15)*4):
//   hoists 8 float4 X loads (rows m4..m4+3 x f-quad, slices g and g+4),
//   d1/d2 dot-partials in-register, in-register 4x4 transpose via 2x cvt_pk -> ds_write_b64.
// Two LDS passes (slices g / g+4), each: write tile -> barrier -> b128 read + 32B XT store.
// d1/d2: shfl-reduce over fq lanes -> group partials in LDS -> t<64 sums 4 groups, plain store
// (no atomics -> no d-memset; block owns rows exclusively).
__global__ __launch_bounds__(1024)
void k_prep(const float* __restrict__ X, const float* __restrict__ ws,
            u16* __restrict__ XT, float* __restrict__ d1acc, float* __restrict__ d2acc){
    __shared__ u16 tile[4][64][TSTR2];   // 36 KB: [slice-group][f 64][m 64 +pad]
    __shared__ float dpart[2][4][64];    // 2 KB group-partial row dots

    const int t   = threadIdx.x;
    const int id  = blockIdx.x + (blockIdx.y << 4);   // 0..255
    const int xcd = id & 7, slot = id >> 3;
    const int b   = (xcd << 1) | (slot >> 4);
    const int m0  = (slot & 15) << 6;

    const int g    = t >> 8;             // slice group 0..3
    const int tid2 = t & 255;
    const int mg   = tid2 >> 4;          // 0..15
    const int m4   = mg * 4;
    const int fq   = (tid2 & 15) * 4;

    // hoisted loads: v[p][i] = X[b][m0+m4+i][(p*4+g)*64 + fq .. +3]
    float4 v[2][4];
    #pragma unroll
    for(int p=0;p<2;p++){
        const float* Xb = X + ((size_t)(b*N_ + m0 + m4))*F_ + (p*4+g)*64 + fq;
        #pragma unroll
        for(int i=0;i<4;i++) v[p][i] = *(const float4*)(Xb + (size_t)i*F_);
    }

    // d1/d2 partials over this thread's 128 f (slices g, g+4) for rows m4..m4+3
    float d1p[4]={0.f,0.f,0.f,0.f}, d2p[4]={0.f,0.f,0.f,0.f};
    #pragma unroll
    for(int p=0;p<2;p++){
        float4 w1q = *(const float4*)(ws + (p*4+g)*64 + fq);
        float4 w2q = *(const float4*)(ws + 512 + (p*4+g)*64 + fq);
        #pragma unroll
        for(int i=0;i<4;i++){
            d1p[i] += v[p][i].x*w1q.x + v[p][i].y*w1q.y + v[p][i].z*w1q.z + v[p][i].w*w1q.w;
            d2p[i] += v[p][i].x*w2q.x + v[p][i].y*w2q.y + v[p][i].z*w2q.z + v[p][i].w*w2q.w;
        }
    }

    // pass p LDS write: 4x4 register transpose, m-packed b64 rows at f = s*64+fq+j
    // cvt_pk(lo,hi) = bf(lo) | bf(hi)<<16 (memory order m4+0, m4+1 ...)
    #define TPOSE(P) { \
        u32 l0 = cvt_pk_bf16(v[P][0].x, v[P][1].x), h0 = cvt_pk_bf16(v[P][2].x, v[P][3].x); \
        *(uint2*)&tile[g][fq+0][m4] = (uint2){l0,h0}; \
        u32 l1 = cvt_pk_bf16(v[P][0].y, v[P][1].y), h1 = cvt_pk_bf16(v[P][2].y, v[P][3].y); \
        *(uint2*)&tile[g][fq+1][m4] = (uint2){l1,h1}; \
        u32 l2 = cvt_pk_bf16(v[P][0].z, v[P][1].z), h2 = cvt_pk_bf16(v[P][2].z, v[P][3].z); \
        *(uint2*)&tile[g][fq+2][m4] = (uint2){l2,h2}; \
        u32 l3 = cvt_pk_bf16(v[P][0].w, v[P][1].w), h3 = cvt_pk_bf16(v[P][2].w, v[P][3].w); \
        *(uint2*)&tile[g][fq+3][m4] = (uint2){l3,h3}; \
    }
    // pass XT out: 64 f-rows x 4 m-units of 16; 2x b128 LDS read (2-way, free) + 32B store
    const int f_loc = tid2 >> 2;
    const int mo    = (tid2 & 3) * 16;
    #define XTOUT(P) { \
        uint4 q0 = *(const uint4*)&tile[g][f_loc][mo]; \
        uint4 q1 = *(const uint4*)&tile[g][f_loc][mo+8]; \
        u16* dst = XT + ((size_t)(b*F_ + (P*4+g)*64 + f_loc))*N_ + m0 + mo; \
        *(uint4*)dst = q0; *(uint4*)(dst+8) = q1; \
    }

    TPOSE(0)
    __syncthreads();
    XTOUT(0)
    __syncthreads();                 // tile consumed; safe to overwrite
    TPOSE(1)
    // reduce d-partials over the 16 fq lanes (lane bits 0..3), store group partials
    #pragma unroll
    for(int s2=1;s2<16;s2<<=1){
        #pragma unroll
        for(int i=0;i<4;i++){ d1p[i] += __shfl_xor(d1p[i],s2,64); d2p[i] += __shfl_xor(d2p[i],s2,64); }
    }
    if((t & 15) == 0){
        #pragma unroll
        for(int i=0;i<4;i++){ dpart[0][g][m4+i] = d1p[i]; dpart[1][g][m4+i] = d2p[i]; }
    }
    __syncthreads();                 // pass-1 tile + dpart visible
    XTOUT(1)
    if(t < 64){
        float s1 = dpart[0][0][t] + dpart[0][1][t] + dpart[0][2][t] + dpart[0][3][t];
        float s2 = dpart[1][0][t] + dpart[1][1][t] + dpart[1][2][t] + dpart[1][3][t];
        d1acc[b*N_ + m0 + t] = s1;
        d2acc[b*N_ + m0 + t] = s2;
    }
}

// ---- kernel 3: fused scores+softmax+PV+ELU, producer/consumer, 16 waves ----
// (VERBATIM round-5 — 66 us known-good)
__global__ __launch_bounds__(1024, 4)
void k_main(const u16* __restrict__ XT, const int* __restrict__ adj,
            const float* __restrict__ d1acc, const float* __restrict__ d2acc,
            float* __restrict__ out){
    __shared__ u16 xbuf[3][2][8192];   // 96 KB triple-buffered X tiles
    __shared__ u32 lds_e2[N_];         // 4 KB exp(f2)/exp(.2 f2) bf16-pair table
    __shared__ u16 pbuf[2][4][512];    // 8 KB P A-fragments [buf][nsub][lane*8]
    __shared__ float dsums[64];        // row softmax denominators

    const int t    = threadIdx.x;
    const int lane = t & 63;
    const int wv   = t >> 6;           // 0..15
    const int nsub = wv & 3;           // consumer: row-group of 16
    const int fq   = wv >> 2;          // consumer: f-quarter of 128
    const int id   = blockIdx.x + (blockIdx.y << 4);
    const int xcd  = id & 7, slot = id >> 3;
    const int b    = (xcd << 1) | (slot >> 4);
    const int n0   = (slot & 15) << 6;
    const int r16  = lane & 15;
    const int quad = lane >> 4;
    const int rowL = lane >> 4;        // producer: row 0..3 within wave's quartet
    const int qL   = lane & 15;        // producer: col-pair index (cols qL*2, qL*2+1)

    // exp(f2)/exp(.2*f2) bf16-pair table: 1 entry/thread
    {
        float dv = d2acc[(size_t)b*N_ + t];
        lds_e2[t] = f2bf(__expf(dv)) | (f2bf(__expf(ALPHA*dv))<<16);
    }
    const float d1v  = d1acc[b*N_ + n0 + wv*4 + rowL];
    const float e1pL = __expf(d1v);
    const float e1nL = __expf(ALPHA*d1v);
    const int* adjLane = adj + ((size_t)(b*N_ + n0 + wv*4 + rowL))*N_ + qL*2;
    const u16* XTb = XT + (size_t)b*F_*N_;

    float dsum = 0.f;
    const int pOff = ((wv&3)*4 + rowL + (qL>>2)*16)*8 + (qL&3)*2;

    auto produce = [&](int c, int pb, int2 ad){
        uint2 ev = *(const uint2*)(&lds_e2[c*32 + qL*2]);
        float p0 = fmaxf(e1pL*bflo(ev.x), e1nL*bfhi(ev.x)); p0 = ad.x ? p0 : 0.f;
        float p1 = fmaxf(e1pL*bflo(ev.y), e1nL*bfhi(ev.y)); p1 = ad.y ? p1 : 0.f;
        dsum += p0 + p1;
        *(u32*)(&pbuf[pb][wv>>2][pOff]) = cvt_pk_bf16(p0, p1);
    };
    auto stage = [&](int mcol, u16 (*buf)[8192]){
        #pragma unroll
        for(int k=0;k<2;k++){
            int idx = wv*2 + k, fhh = idx>>4, c = idx&15;
            const u16* g = XTb + (size_t)(fhh*256 + c*16 + r16)*N_ + mcol + quad*8;
            gload_lds16(g, &buf[fhh][c*512]);
        }
    };

    __syncthreads();                       // lds_e2 ready
    { int2 ad0 = *(const int2*)(adjLane); produce(0, 0, ad0); }
    stage(0,  xbuf[0]);
    int2 adU = *(const int2*)(adjLane + 32);   // adj chunk 1
    stage(32, xbuf[1]);
    asm volatile("s_waitcnt lgkmcnt(0)" ::: "memory");
    __syncthreads();                       // P[0] + chunks 0,1 resident (full drain, one-time)

    float4v acc[8];
    #pragma unroll
    for(int i=0;i<8;i++) acc[i] = (float4v){0.f,0.f,0.f,0.f};

    int db = 0;
    for(int i=0;i<32;i++){
        asm volatile("s_waitcnt vmcnt(2) lgkmcnt(0)\n\ts_barrier" ::: "memory");

        // body VMEM (uniform 3/wave): adj chunk i+2, stage chunk i+2 (dummies wrap at tail)
        const int ms = (i*32 + 64) & (N_-1);
        int2 adV = *(const int2*)(adjLane + ms);
        int dbw = db + 2; if(dbw >= 3) dbw -= 3;
        stage(ms, xbuf[dbw]);

        if(i < 31) produce(i+1, (i+1)&1, adU);   // P[i+1] from adj[i+1] (loaded last body)

        Frag af;
        { uint4 aw = *(const uint4*)(&pbuf[i&1][nsub][lane*8]);
          af.u[0]=aw.x; af.u[1]=aw.y; af.u[2]=aw.z; af.u[3]=aw.w; }
        const u16* bb = &xbuf[db][fq>>1][(fq&1)*8*512 + lane*8];   // lane-linear ds_read_b128
        #pragma unroll
        for(int ct=0; ct<8; ct++){
            uint4 bw = *(const uint4*)(bb + ct*512);
            Frag bf_; bf_.u[0]=bw.x; bf_.u[1]=bw.y; bf_.u[2]=bw.z; bf_.u[3]=bw.w;
            acc[ct] = __builtin_amdgcn_mfma_f32_16x16x32_bf16(af.s, bf_.s, acc[ct], 0, 0, 0);
        }
        adU = adV;
        db = (db==2) ? 0 : db+1;
    }

    // ---- softmax denominators: reduce over qL (lane bits 0..3), one value per row ----
    asm volatile("s_waitcnt vmcnt(0) lgkmcnt(0)" ::: "memory");   // drain tail dummy DMAs
    dsum += __shfl_xor(dsum, 1, 64);
    dsum += __shfl_xor(dsum, 2, 64);
    dsum += __shfl_xor(dsum, 4, 64);
    dsum += __shfl_xor(dsum, 8, 64);
    if(qL == 0) dsums[wv*4 + rowL] = dsum;
    __syncthreads();
    float invr[4];
    #pragma unroll
    for(int r=0;r<4;r++) invr[r] = 1.0f / fmaxf(dsums[nsub*16 + quad*4 + r], 1e-30f);

    // ---- epilogue: scale, ELU, fp32 store ----
    #pragma unroll
    for(int ct=0; ct<8; ct++){
        #pragma unroll
        for(int r=0;r<4;r++){
            float v = acc[ct][r] * invr[r];
            v = (v > 0.f) ? v : (__expf(v) - 1.f);
            int n_out = n0 + nsub*16 + quad*4 + r;
            out[((size_t)(b*N_ + n_out))*F_ + fq*128 + ct*16 + r16] = v;
        }
    }
}

extern "C" void kernel_launch(void* const* d_in, const int* in_sizes, int n_in,
                              void* d_out, int out_size, void* d_ws, size_t ws_size,
                              hipStream_t stream) {
    const float* X  = (const float*)d_in[0];   // [16,1024,512] fp32
    const int* adj  = (const int*)d_in[1];     // [16,1024,1024] int32
    const float* W  = (const float*)d_in[2];   // [512,512] fp32
    const float* a1 = (const float*)d_in[3];   // [512]
    const float* a2 = (const float*)d_in[4];   // [512]
    float* out = (float*)d_out;                // [16,1024,512] fp32

    float* ws    = (float*)d_ws;
    float* d1acc = ws + 1024;                  // fully written by k_prep (no memset needed)
    float* d2acc = ws + 1024 + 16384;
    u16*  XT     = (u16*)(ws + 50176);         // 16.78 MB bf16 [b][f][m]

    hipMemsetAsync(ws, 0, 1024*sizeof(float), stream);    // zero w1/w2 only
    k_w12<<<64, 256, 0, stream>>>(W, a1, a2, ws);
    k_prep<<<dim3(16, 16), 1024, 0, stream>>>(X, ws, XT, d1acc, d2acc);
    k_main<<<dim3(16, 16), 1024, 0, stream>>>(XT, adj, d1acc, d2acc, out);
}